// Round 7
// baseline (271.726 us; speedup 1.0000x reference)
//
#include <hip/hip_runtime.h>

// Persistent fused 2-layer LSTM + FC + softmax for MI355X (gfx950).
// B=2048, T=256, H=64, IN=42. 256 blocks x 512 threads; block owns 8 rows.
// Waves 0-3 (A): layer0(step i); waves 4-7 (B): layer1(step i-1).
//
// R15 = R14 (174us dispatch) + counted-waitcnt barrier in the hot loop:
// __syncthreads() emits s_waitcnt vmcnt(0) lgkmcnt(0) before s_barrier,
// which drained the A-waves' depth-2 x prefetch at EVERY step -> every
// iteration ate full L2/L3 load latency. The x loads land in private
// registers (no cross-wave visibility needed), so the barrier only needs
// lgkmcnt(0) (publish the h ds_writes). Raw s_barrier + explicit
// lgkmcnt(0) keeps x loads in flight across the barrier; the compiler
// inserts its own counted vmcnt before cvtX consumes them (1 step old).
//
// Carried from R14:
//  - x feeds layer0 MFMA chunks 2,3 from per-lane global loads (no stager,
//    no x LDS traffic); pad-row garbage lands in discarded D rows; k>=106
//    zero weight cols mask the tail; kOfsMax clamp keeps loads in-bounds.
//  - common-denominator activations: 7 trans/cell (5 exp2 + 2 rcp).
//  - bias as MFMA C operand; weights pre-scaled by log2e / 2*log2e.
//  - LDS rows [h 64 | pad 8] (stride 72 f16), 16-row ping-pong slots.

typedef _Float16 f16;
typedef _Float16 f16x2 __attribute__((ext_vector_type(2)));
typedef _Float16 f16x8 __attribute__((ext_vector_type(8)));
typedef float f32x4 __attribute__((ext_vector_type(4)));

namespace {
constexpr int kT = 256;
constexpr int kIn = 42;
constexpr int kH = 64;
constexpr int kRows = 8;          // real batch rows per block
constexpr int kThr = 512;
constexpr int kP = 72;            // LDS row stride in f16 (144 B): [h 64 | pad]
constexpr int kS = 16 * kP;       // one ping-pong slot (16 tile rows)
constexpr float kL2E = 1.44269504088896f;   // log2(e)
constexpr float kM2L = -2.0f * kL2E;
constexpr unsigned kNTot = 2048u * 256u * 42u;   // total floats in x
constexpr unsigned kOfsMax = kNTot - 64u;        // clamp so +63 floats stays in-bounds
}

__device__ __forceinline__ float ex2_(float v) { return __builtin_amdgcn_exp2f(v); }
__device__ __forceinline__ float rcp_(float v) { return __builtin_amdgcn_rcpf(v); }
__device__ __forceinline__ f16x2 pk_(float a, float b) {
  return __builtin_bit_cast(f16x2, __builtin_amdgcn_cvt_pkrtz(a, b));
}
// Barrier that publishes LDS writes but does NOT drain vmem (private x
// prefetch stays in flight). Memory clobber pins ds ops on the correct side.
__device__ __forceinline__ void bar_lds_() {
  asm volatile("s_waitcnt lgkmcnt(0)" ::: "memory");
  __builtin_amdgcn_s_barrier();
}

__global__ __launch_bounds__(kThr, 2)
void lstm_r15_kernel(const float* __restrict__ x,
                     const float* __restrict__ Wih0, const float* __restrict__ Whh0,
                     const float* __restrict__ bih0, const float* __restrict__ bhh0,
                     const float* __restrict__ Wih1, const float* __restrict__ Whh1,
                     const float* __restrict__ bih1, const float* __restrict__ bhh1,
                     const float* __restrict__ Wfc, const float* __restrict__ bfc,
                     float* __restrict__ out) {
  __shared__ __align__(16) f16 xh0[2 * kS];
  __shared__ __align__(16) f16 xh1[2 * kS];
  __shared__ float lg[kRows * 8];

  const int tid = threadIdx.x;
  const int w8 = tid >> 6;
  const bool isA = (w8 < 4);     // A: layer 0; B: layer 1
  const int w = w8 & 3;          // gate-col slice [16w, 16w+16)
  const int l = tid & 63;
  const int c = l & 15;
  const int quad = l >> 4;
  const int row0 = blockIdx.x * kRows;

  for (int i = tid; i < 2 * kS; i += kThr) { xh0[i] = (f16)0; xh1[i] = (f16)0; }

  // ---- one-time: weights as MFMA B-fragments (pre-scaled) + bias4 ----
  f16x8 Bw[4][4];
  f32x4 bias4[4];
#pragma unroll
  for (int a = 0; a < 4; ++a) {
    const int g = (w + 4 * a) * 16 + c;
    const float scale = (a == 2) ? 2.0f * kL2E : kL2E;  // g-gate gets 2*log2e
    const float b = (isA ? (bih0[g] + bhh0[g]) : (bih1[g] + bhh1[g])) * scale;
    bias4[a] = (f32x4){b, b, b, b};
#pragma unroll
    for (int q = 0; q < 4; ++q) {
      f16x8 v;
#pragma unroll
      for (int j = 0; j < 8; ++j) {
        const int k = q * 32 + quad * 8 + j;
        float wv;
        if (isA)  // layer0 A = [h0 (k<64) | x (64<=k<106) | 0]
          wv = (k < 64) ? Whh0[g * kH + k] : (k < 106) ? Wih0[g * kIn + (k - 64)] : 0.f;
        else      // layer1 A = [h0 (k<64) | h1]
          wv = (k < 64) ? Wih1[g * kH + k] : Whh1[g * kH + (k - 64)];
        v[j] = (f16)(wv * scale);
      }
      Bw[a][q] = v;
    }
  }

  // ---- LDS pointers (lane reads tile row c) ----
  const f16* rbh[2];   // h0 chunks 0,1 (A and B)
  rbh[0] = xh0 + c * kP + quad * 8;
  rbh[1] = rbh[0] + kS;
  const f16* rb1[2];   // h1 chunks (B only)
  rb1[0] = xh1 + c * kP + quad * 8;
  rb1[1] = rb1[0] + kS;

  // h writes: cell i2 -> tile row quad*4+i2 (interleaved m-map), col hcol.
  const int hcol = w * 16 + c;
  f16* wp[2];
  {
    f16* base = isA ? xh0 : xh1;
    wp[0] = base + (quad * 4) * kP + hcol;
    wp[1] = wp[0] + kS;
  }

  float cst[2] = {0.f, 0.f};

  // ---- A-wave register x pipeline (prefetch depth 2) ----
  // Lane's x batch row: pad lanes alias a real row; their MFMA products
  // land in discarded D rows. fc3 tail (>=42) is masked by the zero
  // weight columns; kOfsMax clamp keeps loads in-bounds.
  const int xr = ((c >> 2) << 1) | (c & 1);
  const unsigned fc2 = (unsigned)(quad * 8);
  const unsigned fc3 = 32u + (unsigned)(quad * 8);
  unsigned ofs = (unsigned)(row0 + xr) * (unsigned)(kT * kIn);

  float2 rawA[8], rawB[8];
  f16x8 fx2{}, fx3{};

  auto issueX = [&](float2 (&r)[8], unsigned o) {
    const float* p = x + (o < kOfsMax ? o : kOfsMax);
#pragma unroll
    for (int j = 0; j < 4; ++j) {
      r[j]     = *(const float2*)(p + fc2 + 2 * j);
      r[4 + j] = *(const float2*)(p + fc3 + 2 * j);
    }
  };
  auto cvtX = [&](const float2 (&r)[8]) {
    struct H4 { f16x2 a, b, c, d; };
    H4 h2, h3;
    h2.a = pk_(r[0].x, r[0].y);
    h2.b = pk_(r[1].x, r[1].y);
    h2.c = pk_(r[2].x, r[2].y);
    h2.d = pk_(r[3].x, r[3].y);
    h3.a = pk_(r[4].x, r[4].y);
    h3.b = pk_(r[5].x, r[5].y);
    h3.c = pk_(r[6].x, r[6].y);
    h3.d = pk_(r[7].x, r[7].y);
    fx2 = __builtin_bit_cast(f16x8, h2);
    fx3 = __builtin_bit_cast(f16x8, h3);
  };

  if (isA) {
    issueX(rawB, ofs);            // x(0)
    cvtX(rawB);                   // fragX = x(0)
    issueX(rawA, ofs + kIn);      // x(1) in flight
    ofs += 2u * kIn;              // next issue: t = 2
  }
  __syncthreads();  // startup barrier (full drain once is fine)

  // iter i: A computes layer0(t=i) (i<kT), B computes layer1(t=i-1) (i>0).
  auto step = [&](int i, int par, bool even) {
    const int nxt = par ^ 1;
    const bool act = isA ? (i < kT) : (i > 0);

    if (act) {
      f32x4 acc[4];
      if (isA) {
        // x chunks first: register-resident, overlap the h0 ds_reads.
#pragma unroll
        for (int a = 0; a < 4; ++a)
          acc[a] = __builtin_amdgcn_mfma_f32_16x16x32_f16(fx2, Bw[a][2], bias4[a], 0, 0, 0);
#pragma unroll
        for (int a = 0; a < 4; ++a)
          acc[a] = __builtin_amdgcn_mfma_f32_16x16x32_f16(fx3, Bw[a][3], acc[a], 0, 0, 0);
        const f16x8 A0 = __builtin_bit_cast(f16x8, *(const float4*)(rbh[par]));
        const f16x8 A1 = __builtin_bit_cast(f16x8, *(const float4*)(rbh[par] + 32));
#pragma unroll
        for (int a = 0; a < 4; ++a)
          acc[a] = __builtin_amdgcn_mfma_f32_16x16x32_f16(A0, Bw[a][0], acc[a], 0, 0, 0);
#pragma unroll
        for (int a = 0; a < 4; ++a)
          acc[a] = __builtin_amdgcn_mfma_f32_16x16x32_f16(A1, Bw[a][1], acc[a], 0, 0, 0);
      } else {
        const f16x8 A0 = __builtin_bit_cast(f16x8, *(const float4*)(rbh[par]));
        const f16x8 A1 = __builtin_bit_cast(f16x8, *(const float4*)(rbh[par] + 32));
        const f16x8 A2 = __builtin_bit_cast(f16x8, *(const float4*)(rb1[par]));
        const f16x8 A3 = __builtin_bit_cast(f16x8, *(const float4*)(rb1[par] + 32));
#pragma unroll
        for (int a = 0; a < 4; ++a)
          acc[a] = __builtin_amdgcn_mfma_f32_16x16x32_f16(A0, Bw[a][0], bias4[a], 0, 0, 0);
#pragma unroll
        for (int a = 0; a < 4; ++a)
          acc[a] = __builtin_amdgcn_mfma_f32_16x16x32_f16(A1, Bw[a][1], acc[a], 0, 0, 0);
#pragma unroll
        for (int a = 0; a < 4; ++a)
          acc[a] = __builtin_amdgcn_mfma_f32_16x16x32_f16(A2, Bw[a][2], acc[a], 0, 0, 0);
#pragma unroll
        for (int a = 0; a < 4; ++a)
          acc[a] = __builtin_amdgcn_mfma_f32_16x16x32_f16(A3, Bw[a][3], acc[a], 0, 0, 0);
      }

      // common-denominator activation (7 trans/cell: 5 exp2 + 2 rcp)
#pragma unroll
      for (int i2 = 0; i2 < 2; ++i2) {
        const float ei = ex2_(-acc[0][i2]);
        const float ef = ex2_(-acc[1][i2]);
        const float eg = ex2_(-acc[2][i2]);
        const float eo = ex2_(-acc[3][i2]);
        const float pi = 1.0f + ei, pf = 1.0f + ef, pg = 1.0f + eg, po = 1.0f + eo;
        const float mg = 1.0f - eg;
        const float t1 = pi * pg;
        const float t2 = mg * pf;
        const float N  = fmaf(cst[i2], t1, t2);
        const float cn = N * rcp_(t1 * pf);
        cst[i2] = cn;
        const float ec = ex2_(cn * kM2L);
        const float h  = (1.0f - ec) * rcp_(po * (1.0f + ec));
        wp[nxt][i2 * kP] = (f16)h;
      }
    }
    if (isA) {
      if (even) { issueX(rawB, ofs); cvtX(rawA); }   // issue x(i+2), cvt x(i+1)
      else      { issueX(rawA, ofs); cvtX(rawB); }
      ofs += (unsigned)kIn;
    }
    bar_lds_();  // publish h writes (lgkmcnt only); x loads stay in flight
  };

  for (int i = 0; i < kT; i += 2) { step(i, 0, true); step(i + 1, 1, false); }
  step(kT, 0, true);  // drain: B computes h1(T-1) -> xh1 slot 1

  // ---- FC + softmax. Final h1(T-1) is in xh1 slot 1. ----
  if (tid < kRows * 5) {
    const int rr = tid / 5, oo = tid - rr * 5;
    const int m = ((rr >> 1) << 2) | (rr & 1);
    float a = bfc[oo];
#pragma unroll
    for (int j = 0; j < kH; ++j)
      a += (float)xh1[kS + m * kP + j] * Wfc[oo * kH + j];
    lg[rr * 8 + oo] = a;
  }
  __syncthreads();
  if (tid < kRows) {
    const float v0 = lg[tid * 8 + 0], v1 = lg[tid * 8 + 1], v2 = lg[tid * 8 + 2],
                v3 = lg[tid * 8 + 3], v4 = lg[tid * 8 + 4];
    const float m = fmaxf(fmaxf(fmaxf(v0, v1), fmaxf(v2, v3)), v4);
    const float e0 = __expf(v0 - m), e1 = __expf(v1 - m), e2 = __expf(v2 - m),
                e3 = __expf(v3 - m), e4 = __expf(v4 - m);
    const float inv = __fdividef(1.0f, e0 + e1 + e2 + e3 + e4);
    float* o = out + (size_t)(row0 + tid) * 5;
    o[0] = e0 * inv; o[1] = e1 * inv; o[2] = e2 * inv; o[3] = e3 * inv; o[4] = e4 * inv;
  }
}

extern "C" void kernel_launch(void* const* d_in, const int* in_sizes, int n_in,
                              void* d_out, int out_size, void* d_ws, size_t ws_size,
                              hipStream_t stream) {
  (void)in_sizes; (void)n_in; (void)d_ws; (void)ws_size; (void)out_size;
  lstm_r15_kernel<<<dim3(256), dim3(kThr), 0, stream>>>(
      (const float*)d_in[0],
      (const float*)d_in[1], (const float*)d_in[2],
      (const float*)d_in[3], (const float*)d_in[4],
      (const float*)d_in[5], (const float*)d_in[6],
      (const float*)d_in[7], (const float*)d_in[8],
      (const float*)d_in[9], (const float*)d_in[10],
      (float*)d_out);
}